// Round 1
// baseline (385.897 us; speedup 1.0000x reference)
//
#include <hip/hip_runtime.h>
#include <stdint.h>

typedef __bf16 bf16;
typedef __bf16 bf16x8 __attribute__((ext_vector_type(8)));
typedef __bf16 bf16x4 __attribute__((ext_vector_type(4)));
typedef float f32x4 __attribute__((ext_vector_type(4)));
typedef float f32x16 __attribute__((ext_vector_type(16)));

#define DEV static __device__ __forceinline__

// ---------------------------------------------------------------------------
// async global->LDS, 16B per lane. LDS dest is wave-uniform base + lane*16.
// ---------------------------------------------------------------------------
DEV void async_copy16(const bf16* gsrc, const bf16* ldst) {
  __builtin_amdgcn_global_load_lds(
      (__attribute__((address_space(1))) void*)(uintptr_t)gsrc,
      (__attribute__((address_space(3))) void*)(uint32_t)(uintptr_t)ldst,
      16, 0, 0);
}

// ---------------------------------------------------------------------------
// 128x128 (BK=64) bf16 MFMA GEMM mainloop, C = A * B^T, 32x32x16 path.
// A: [M,K] row-major (lda), B: [N,K] row-major (ldb). 256 threads, 4 waves
// in 2x2 grid; each wave owns a 64x64 subtile. (Used by scores/out; the
// QKV GEMM moved to the 256x256 never-drain pipeline below in R5.)
// ---------------------------------------------------------------------------
DEV void gemm_tile32(const bf16* __restrict__ A, const bf16* __restrict__ B,
                     int lda, int ldb, int kTiles,
                     bf16* As, bf16* Bs, f32x16 acc[2][2]) {
  const int tid  = threadIdx.x;
  const int wave = tid >> 6;
  const int lane = tid & 63;
  const int wm = (wave >> 1) * 64;
  const int wn = (wave & 1) * 64;
  const int rf = lane & 31;          // fragment row (m/n) within 32
  const int kh = (lane >> 5) * 8;    // k-half offset within 16
  const int sw = (lane & 7) * 8;     // xor for swizzled element offset

  const int srow = tid >> 3;
  const int scol = ((tid & 7) ^ (srow & 7)) * 8;
  const bf16* Ag = A + (size_t)srow * lda + scol;
  const bf16* Bg = B + (size_t)srow * ldb + scol;
  bf16* Asw = As + wave * 512;
  bf16* Bsw = Bs + wave * 512;

  for (int kt = 0; kt < kTiles; ++kt) {
    __syncthreads();
    const bf16* ag = Ag + kt * 64;
    const bf16* bg = Bg + kt * 64;
#pragma unroll
    for (int i = 0; i < 4; ++i) {
      async_copy16(ag + (size_t)(i * 32) * lda, Asw + i * 2048);
      async_copy16(bg + (size_t)(i * 32) * ldb, Bsw + i * 2048);
    }
    __syncthreads();
#pragma unroll
    for (int ks = 0; ks < 4; ++ks) {
      const int off = (ks * 16 + kh) ^ sw;
      bf16x8 a0 = *(const bf16x8*)&As[(wm + rf) * 64 + off];
      bf16x8 a1 = *(const bf16x8*)&As[(wm + 32 + rf) * 64 + off];
      bf16x8 b0 = *(const bf16x8*)&Bs[(wn + rf) * 64 + off];
      bf16x8 b1 = *(const bf16x8*)&Bs[(wn + 32 + rf) * 64 + off];
      acc[0][0] = __builtin_amdgcn_mfma_f32_32x32x16_bf16(a0, b0, acc[0][0], 0, 0, 0);
      acc[0][1] = __builtin_amdgcn_mfma_f32_32x32x16_bf16(a0, b1, acc[0][1], 0, 0, 0);
      acc[1][0] = __builtin_amdgcn_mfma_f32_32x32x16_bf16(a1, b0, acc[1][0], 0, 0, 0);
      acc[1][1] = __builtin_amdgcn_mfma_f32_32x32x16_bf16(a1, b1, acc[1][1], 0, 0, 0);
    }
  }
}

// 32x32 C/D (m74/m101): col=lane&31, row=(reg&3)+8*(reg>>2)+4*(lane>>5).
#define EPILOGUE32(STMT)                                                     \
  do {                                                                       \
    const int lane = threadIdx.x & 63, wave = threadIdx.x >> 6;              \
    const int colb = n0 + (wave & 1) * 64 + (lane & 31);                     \
    const int rowb = m0 + (wave >> 1) * 64 + (lane >> 5) * 4;                \
    _Pragma("unroll") for (int i = 0; i < 2; ++i)                            \
      _Pragma("unroll") for (int reg = 0; reg < 16; ++reg) {                 \
        size_t row = rowb + i * 32 + (reg & 3) + 8 * (reg >> 2);             \
        _Pragma("unroll") for (int j = 0; j < 2; ++j) {                      \
          size_t col = colb + j * 32;                                        \
          float val = acc[i][j][reg];                                        \
          STMT;                                                              \
        }                                                                    \
      }                                                                      \
  } while (0)

// ---------------------------------------------------------------------------
// Kernel 1: merged cast — x (16.78M floats) then Wq|Wk|Wv (3.15M floats).
// ---------------------------------------------------------------------------
__global__ __launch_bounds__(256) void k_cast_all(const float* __restrict__ X,
                                                  const float* __restrict__ Wq,
                                                  const float* __restrict__ Wk,
                                                  const float* __restrict__ Wv,
                                                  bf16* __restrict__ Xb,
                                                  bf16* __restrict__ Wb) {
  int i = blockIdx.x * 256 + threadIdx.x;  // float4 index, 4980736 total
  const float* src;
  bf16* dst;
  int off;
  if (i < 4194304) {            // x
    src = X; dst = Xb; off = i;
  } else {                      // weights, 262144 float4 per matrix
    int j = i - 4194304;
    int which = j >> 18;
    src = (which == 0) ? Wq : ((which == 1) ? Wk : Wv);
    dst = Wb + (size_t)(j >> 18) * 1048576;
    off = j & 262143;
  }
  float4 v = ((const float4*)src)[off];
  bf16x4 o = {(bf16)v.x, (bf16)v.y, (bf16)v.z, (bf16)v.w};
  ((bf16x4*)dst)[off] = o;
}

// ---------------------------------------------------------------------------
// Kernel 2: QKV = Xb @ Wb^T (M=16384, N=3072, K=1024), bf16, ldc=3072.
//
// R5: 256x256 tile, BK=32, 512 threads (8 waves, 2M x 4N; per-wave 128x64,
// acc[8][4]). Never-drain software pipeline (T3/T4): ring-2 LDS K-tile
// slots (2 x 32 KiB), raw s_barrier + counted "s_waitcnt vmcnt(4)".
// Invariant at iter t: slot t&1 holds tile t (landed), stage of t+1 in
// flight. Body: compute(t) -> lgkmcnt(0)+barrier (slot dead) -> issue
// stage(t+2) into slot t&1 -> vmcnt(4) (waits tile t+1 ONLY; tile t+2's 4
// loads ride across the barrier) -> barrier. The old structure's implicit
// vmcnt(0)+lgkmcnt(0) drain before every __syncthreads was the diagnosed
// stall (MfmaUtil 33%, HBM 20%, occupancy 25% -- nothing near roofline).
//
// LDS swizzle (conflict-free for ds_read_b128 AND the linear
// global_load_lds writes): rows paired into 128 B superrows (rho=row>>1,
// 8 x 16B granules). Physical granule p of superrow rho holds logical
// granule sigma = p ^ (rho&7), where sigma>>2 = row parity, sigma&3 =
// k-colseg. A wave's frag read (16 rows x 4 k-colsegs) touches each
// bank-quad exactly 2x (2-way = free, m136). Swizzle is folded into the
// per-lane GLOBAL source address; LDS dest stays linear (m104/m173).
// sched_barrier(0) fences around every s_barrier: hipcc otherwise hoists
// memory ops across raw barriers (rule #18).
// ---------------------------------------------------------------------------
__global__ __launch_bounds__(512, 2) void k_gemm_qkv(
    const bf16* __restrict__ X, const bf16* __restrict__ W,
    const int* __restrict__ lens, bf16* __restrict__ QKV) {
  const int n0 = blockIdx.x * 256;
  const int m0 = blockIdx.y * 256;
  if (n0 >= 1024 && (m0 & 2047) >= lens[m0 >> 11]) return;  // block-uniform
  __shared__ __align__(16) char smem[65536];  // 2 slots x (A 16K | B 16K)

  const int tid = threadIdx.x;
  const int lane = tid & 63, wid = tid >> 6;

  // staging source geometry: physical granule g -> (global row, col)
  int grow0, gcol0, grow1, gcol1;
  {
    int g = tid, rho = g >> 3, sig = (g & 7) ^ (rho & 7);
    grow0 = 2 * rho + (sig >> 2); gcol0 = (sig & 3) * 8;
    g = tid + 512; rho = g >> 3; sig = (g & 7) ^ (rho & 7);
    grow1 = 2 * rho + (sig >> 2); gcol1 = (sig & 3) * 8;
  }
  const bf16* pa0 = X + (size_t)(m0 + grow0) * 1024 + gcol0;
  const bf16* pa1 = X + (size_t)(m0 + grow1) * 1024 + gcol1;
  const bf16* pb0 = W + (size_t)(n0 + grow0) * 1024 + gcol0;
  const bf16* pb1 = W + (size_t)(n0 + grow1) * 1024 + gcol1;

#define QKV_STAGE(kt, slot)                                  \
  do {                                                       \
    const int ko_ = (kt) * 32;                               \
    char* sb_ = smem + (slot) * 32768 + wid * 1024;          \
    async_copy16(pa0 + ko_, (const bf16*)sb_);               \
    async_copy16(pa1 + ko_, (const bf16*)(sb_ + 8192));      \
    async_copy16(pb0 + ko_, (const bf16*)(sb_ + 16384));     \
    async_copy16(pb1 + ko_, (const bf16*)(sb_ + 24576));     \
  } while (0)

  // per-lane read addresses (bytes): row r -> rho=r>>1, eps=r&1;
  // byte = rho*128 + ((eps*4 + kseg) ^ (rho&7))*16.  Frag step i*16 rows
  // = 8 superrows: rho&7 invariant -> constant +1024 B per frag.
  const int mf = lane & 15, jb = lane >> 4;
  const int wm = (wid >> 2) * 128, wn = (wid & 3) * 64;
  const uint32_t pbyte = (uint32_t)((((((mf & 1) << 2) | jb) ^ ((mf >> 1) & 7))) * 16);
  const uint32_t laneA = (uint32_t)(wm * 64 + (mf >> 1) * 128) + pbyte;
  const uint32_t laneB = 16384u + (uint32_t)(wn * 64 + (mf >> 1) * 128) + pbyte;

  f32x4 acc[8][4] = {};

  // prologue: tiles 0,1 staged; wait tile 0 (tile 1's 4 loads stay in flight)
  QKV_STAGE(0, 0);
  QKV_STAGE(1, 1);
  asm volatile("s_waitcnt vmcnt(4)" ::: "memory");
  __builtin_amdgcn_sched_barrier(0);
  __builtin_amdgcn_s_barrier();
  __builtin_amdgcn_sched_barrier(0);

  for (int t = 0; t < 32; ++t) {
    const char* As = smem + (t & 1) * 32768 + laneA;
    const char* Bs = smem + (t & 1) * 32768 + laneB;
    bf16x8 af[8], bfr[4];
#pragma unroll
    for (int i = 0; i < 8; ++i) af[i] = *(const bf16x8*)(As + i * 1024);
#pragma unroll
    for (int j = 0; j < 4; ++j) bfr[j] = *(const bf16x8*)(Bs + j * 1024);
    __builtin_amdgcn_s_setprio(1);
#pragma unroll
    for (int i = 0; i < 8; ++i)
#pragma unroll
      for (int j = 0; j < 4; ++j)
        acc[i][j] = __builtin_amdgcn_mfma_f32_16x16x32_bf16(af[i], bfr[j], acc[i][j], 0, 0, 0);
    __builtin_amdgcn_s_setprio(0);
    asm volatile("s_waitcnt lgkmcnt(0)" ::: "memory");
    __builtin_amdgcn_sched_barrier(0);
    __builtin_amdgcn_s_barrier();      // all waves done reading slot t&1
    __builtin_amdgcn_sched_barrier(0);
    const int nx = (t + 2 < 32) ? t + 2 : 31;  // clamped tail restage: benign
    QKV_STAGE(nx, t & 1);
    asm volatile("s_waitcnt vmcnt(4)" ::: "memory");  // tile t+1 landed
    __builtin_amdgcn_sched_barrier(0);
    __builtin_amdgcn_s_barrier();      // tile t+1 visible block-wide
    __builtin_amdgcn_sched_barrier(0);
  }
#undef QKV_STAGE

  // epilogue: 16x16 C/D layout (m89/m91): col=lane&15, row=(lane>>4)*4+reg.
  const float qscale = (n0 < 1024) ? 0.03125f : 1.0f;  // block-uniform
  const int colb = n0 + wn + mf;
  const int rowb = m0 + wm + jb * 4;
#pragma unroll
  for (int i = 0; i < 8; ++i)
#pragma unroll
    for (int r = 0; r < 4; ++r) {
      bf16* dst = QKV + (size_t)(rowb + i * 16 + r) * 3072 + colb;
#pragma unroll
      for (int j = 0; j < 4; ++j) dst[j * 16] = (bf16)(acc[i][j][r] * qscale);
    }
}

// ---------------------------------------------------------------------------
// Kernel 3: transpose V part of QKV -> Vt[b][d][s]. Skip s-blocks >= kmax.
// ---------------------------------------------------------------------------
__global__ __launch_bounds__(256) void k_transpose_v(const bf16* __restrict__ QKV,
                                                     const int* __restrict__ lens,
                                                     bf16* __restrict__ Vt) {
  __shared__ bf16 tile[32][33];
  const int b = blockIdx.z;
  const int s0 = blockIdx.x * 32;
  if (s0 >= ((lens[b] + 63) & ~63)) return;
  const int d0 = blockIdx.y * 32;
  const int tx = threadIdx.x, ty = threadIdx.y;  // (32, 8)
#pragma unroll
  for (int i = 0; i < 4; ++i)
    tile[ty + i * 8][tx] = QKV[(size_t)(b * 2048 + s0 + ty + i * 8) * 3072 + 2048 + d0 + tx];
  __syncthreads();
#pragma unroll
  for (int i = 0; i < 4; ++i)
    Vt[(size_t)(b * 1024 + d0 + ty + i * 8) * 2048 + s0 + tx] = tile[tx][ty + i * 8];
}

// ---------------------------------------------------------------------------
// Kernel 4: S = Q @ K^T per batch (Q pre-scaled), bf16. 32x32x16 path
// (L2-resident staging -> MFMA-pipe-bound; R3 measured win). Skip >= len.
// ---------------------------------------------------------------------------
__global__ __launch_bounds__(256) void k_gemm_scores(const bf16* __restrict__ QKV,
                                                     const int* __restrict__ lens,
                                                     bf16* __restrict__ S) {
  const int b = blockIdx.z;
  const int len = lens[b];
  const int n0 = blockIdx.x * 128;  // key tile
  if (n0 >= len) return;            // uniform per block
  const int m0 = blockIdx.y * 128;  // query tile
  __shared__ __align__(16) bf16 As[128 * 64];
  __shared__ __align__(16) bf16 Bs[128 * 64];
  const bf16* Q = QKV + (size_t)b * 2048 * 3072;
  const bf16* K = Q + 1024;
  f32x16 acc[2][2] = {};
  gemm_tile32(Q + (size_t)m0 * 3072, K + (size_t)n0 * 3072, 3072, 3072, 16, As, Bs, acc);
  bf16* Sb = S + (size_t)b * 2048 * 2048;
  EPILOGUE32(Sb[row * 2048 + col] = (bf16)val);
}

// ---------------------------------------------------------------------------
// Kernel 5: masked softmax per row, in place (S -> P). Loads below len,
// stores below kmax = ceil64(len), zeros on [len, kmax).
// ---------------------------------------------------------------------------
__global__ __launch_bounds__(256) void k_softmax(bf16* __restrict__ S,
                                                 const int* __restrict__ lens) {
  const int row = blockIdx.x;  // 0..16383 (= b*2048 + q)
  const int len = lens[row >> 11];
  const int kmax = (len + 63) & ~63;
  bf16* Sr = S + (size_t)row * 2048;
  const int tid = threadIdx.x;
  const int base = tid * 8;
  __shared__ float red[4];

  float f[8];
  if (base < len) {
    bf16x8 v = ((const bf16x8*)Sr)[tid];
#pragma unroll
    for (int e = 0; e < 8; ++e) f[e] = (base + e < len) ? (float)v[e] : -1e30f;
  } else {
#pragma unroll
    for (int e = 0; e < 8; ++e) f[e] = -1e30f;
  }
  float m = -1e30f;
#pragma unroll
  for (int e = 0; e < 8; ++e) m = fmaxf(m, f[e]);
#pragma unroll
  for (int off = 32; off; off >>= 1) m = fmaxf(m, __shfl_xor(m, off));
  if ((tid & 63) == 0) red[tid >> 6] = m;
  __syncthreads();
  m = fmaxf(fmaxf(red[0], red[1]), fmaxf(red[2], red[3]));
  __syncthreads();

  float s = 0.f;
#pragma unroll
  for (int e = 0; e < 8; ++e) {
    float p = (base + e < len) ? __expf(f[e] - m) : 0.f;
    f[e] = p;
    s += p;
  }
#pragma unroll
  for (int off = 32; off; off >>= 1) s += __shfl_xor(s, off);
  if ((tid & 63) == 0) red[tid >> 6] = s;
  __syncthreads();
  s = red[0] + red[1] + red[2] + red[3];
  const float inv = 1.f / s;

  if (base < kmax) {
    bf16x8 o;
#pragma unroll
    for (int e = 0; e < 8; ++e) o[e] = (bf16)(f[e] * inv);
    ((bf16x8*)Sr)[tid] = o;
  }
}

// ---------------------------------------------------------------------------
// Kernel 6: O = P @ Vt^T per batch (M=2048, N=1024, K=ceil(len,64)), fp32.
// 32x32x16 path (same rationale as scores).
// ---------------------------------------------------------------------------
__global__ __launch_bounds__(256) void k_gemm_out(const bf16* __restrict__ P,
                                                  const bf16* __restrict__ Vt,
                                                  const int* __restrict__ lens,
                                                  float* __restrict__ Out) {
  const int b = blockIdx.z;
  const int kTiles = (lens[b] + 63) >> 6;  // P is zero beyond len within tile
  const int n0 = blockIdx.x * 128;  // over d (1024)
  const int m0 = blockIdx.y * 128;  // over queries
  __shared__ __align__(16) bf16 As[128 * 64];
  __shared__ __align__(16) bf16 Bs[128 * 64];
  const bf16* Pb = P + (size_t)b * 2048 * 2048;
  const bf16* Vb = Vt + (size_t)b * 1024 * 2048;
  f32x16 acc[2][2] = {};
  gemm_tile32(Pb + (size_t)m0 * 2048, Vb + (size_t)n0 * 2048, 2048, 2048, kTiles, As, Bs, acc);
  float* Ob = Out + (size_t)b * 2048 * 1024;
  EPILOGUE32(Ob[row * 1024 + col] = val);
}

// ---------------------------------------------------------------------------
// Workspace layout (bytes):
//   [0,   32M)   Xb   (dead after GEMM1)  \ overlapped by
//   [32M, 38M)   Wb   (dead after GEMM1)  /  S/P: [0, 64M)
//   [64M, 160M)  QKV  bf16 [16384][3072]
//   [160M,192M)  Vt   bf16 [8][1024][2048]
// ---------------------------------------------------------------------------
extern "C" void kernel_launch(void* const* d_in, const int* in_sizes, int n_in,
                              void* d_out, int out_size, void* d_ws, size_t ws_size,
                              hipStream_t stream) {
  const float* x   = (const float*)d_in[0];
  const int* lens  = (const int*)d_in[1];
  const float* Wq  = (const float*)d_in[2];
  const float* Wk  = (const float*)d_in[3];
  const float* Wv  = (const float*)d_in[4];
  float* out = (float*)d_out;

  char* ws = (char*)d_ws;
  bf16* S   = (bf16*)(ws);                 // 64 MiB (scores, then P in place)
  bf16* Xb  = (bf16*)(ws);                 // 32 MiB, overlaps S (dead first)
  bf16* Wb  = (bf16*)(ws + 33554432);      // 6 MiB, overlaps S
  bf16* QKV = (bf16*)(ws + 67108864);      // 96 MiB
  bf16* Vt  = (bf16*)(ws + 167772160);     // 32 MiB

  k_cast_all<<<19456, 256, 0, stream>>>(x, Wq, Wk, Wv, Xb, Wb);
  k_gemm_qkv<<<dim3(12, 64), 512, 0, stream>>>(Xb, Wb, lens, QKV);
  k_transpose_v<<<dim3(64, 32, 8), dim3(32, 8), 0, stream>>>(QKV, lens, Vt);
  k_gemm_scores<<<dim3(16, 16, 8), 256, 0, stream>>>(QKV, lens, S);
  k_softmax<<<16384, 256, 0, stream>>>(S, lens);
  k_gemm_out<<<dim3(8, 16, 8), 256, 0, stream>>>(S, Vt, lens, out);
}

// Round 3
// 376.108 us; speedup vs baseline: 1.0260x; 1.0260x over previous
//
#include <hip/hip_runtime.h>
#include <stdint.h>

typedef __bf16 bf16;
typedef __bf16 bf16x8 __attribute__((ext_vector_type(8)));
typedef __bf16 bf16x4 __attribute__((ext_vector_type(4)));
typedef float f32x4 __attribute__((ext_vector_type(4)));
typedef float f32x16 __attribute__((ext_vector_type(16)));

#define DEV static __device__ __forceinline__
#define SB0() __builtin_amdgcn_sched_barrier(0)

// ---------------------------------------------------------------------------
// async global->LDS, 16B per lane. LDS dest is wave-uniform base + lane*16.
// ---------------------------------------------------------------------------
DEV void async_copy16(const bf16* gsrc, const bf16* ldst) {
  __builtin_amdgcn_global_load_lds(
      (__attribute__((address_space(1))) void*)(uintptr_t)gsrc,
      (__attribute__((address_space(3))) void*)(uint32_t)(uintptr_t)ldst,
      16, 0, 0);
}

DEV f32x4 MF(bf16x8 a, bf16x8 b, f32x4 c) {
  return __builtin_amdgcn_mfma_f32_16x16x32_bf16(a, b, c, 0, 0, 0);
}

// ---------------------------------------------------------------------------
// 128x128 (BK=64) bf16 MFMA GEMM mainloop, C = A * B^T, 32x32x16 path.
// Used by scores/out (unchanged this round).
// ---------------------------------------------------------------------------
DEV void gemm_tile32(const bf16* __restrict__ A, const bf16* __restrict__ B,
                     int lda, int ldb, int kTiles,
                     bf16* As, bf16* Bs, f32x16 acc[2][2]) {
  const int tid  = threadIdx.x;
  const int wave = tid >> 6;
  const int lane = tid & 63;
  const int wm = (wave >> 1) * 64;
  const int wn = (wave & 1) * 64;
  const int rf = lane & 31;
  const int kh = (lane >> 5) * 8;
  const int sw = (lane & 7) * 8;

  const int srow = tid >> 3;
  const int scol = ((tid & 7) ^ (srow & 7)) * 8;
  const bf16* Ag = A + (size_t)srow * lda + scol;
  const bf16* Bg = B + (size_t)srow * ldb + scol;
  bf16* Asw = As + wave * 512;
  bf16* Bsw = Bs + wave * 512;

  for (int kt = 0; kt < kTiles; ++kt) {
    __syncthreads();
    const bf16* ag = Ag + kt * 64;
    const bf16* bg = Bg + kt * 64;
#pragma unroll
    for (int i = 0; i < 4; ++i) {
      async_copy16(ag + (size_t)(i * 32) * lda, Asw + i * 2048);
      async_copy16(bg + (size_t)(i * 32) * ldb, Bsw + i * 2048);
    }
    __syncthreads();
#pragma unroll
    for (int ks = 0; ks < 4; ++ks) {
      const int off = (ks * 16 + kh) ^ sw;
      bf16x8 a0 = *(const bf16x8*)&As[(wm + rf) * 64 + off];
      bf16x8 a1 = *(const bf16x8*)&As[(wm + 32 + rf) * 64 + off];
      bf16x8 b0 = *(const bf16x8*)&Bs[(wn + rf) * 64 + off];
      bf16x8 b1 = *(const bf16x8*)&Bs[(wn + 32 + rf) * 64 + off];
      acc[0][0] = __builtin_amdgcn_mfma_f32_32x32x16_bf16(a0, b0, acc[0][0], 0, 0, 0);
      acc[0][1] = __builtin_amdgcn_mfma_f32_32x32x16_bf16(a0, b1, acc[0][1], 0, 0, 0);
      acc[1][0] = __builtin_amdgcn_mfma_f32_32x32x16_bf16(a1, b0, acc[1][0], 0, 0, 0);
      acc[1][1] = __builtin_amdgcn_mfma_f32_32x32x16_bf16(a1, b1, acc[1][1], 0, 0, 0);
    }
  }
}

// 32x32 C/D (m74/m101): col=lane&31, row=(reg&3)+8*(reg>>2)+4*(lane>>5).
#define EPILOGUE32(STMT)                                                     \
  do {                                                                       \
    const int lane = threadIdx.x & 63, wave = threadIdx.x >> 6;              \
    const int colb = n0 + (wave & 1) * 64 + (lane & 31);                     \
    const int rowb = m0 + (wave >> 1) * 64 + (lane >> 5) * 4;                \
    _Pragma("unroll") for (int i = 0; i < 2; ++i)                            \
      _Pragma("unroll") for (int reg = 0; reg < 16; ++reg) {                 \
        size_t row = rowb + i * 32 + (reg & 3) + 8 * (reg >> 2);             \
        _Pragma("unroll") for (int j = 0; j < 2; ++j) {                      \
          size_t col = colb + j * 32;                                        \
          float val = acc[i][j][reg];                                        \
          STMT;                                                              \
        }                                                                    \
      }                                                                      \
  } while (0)

// ---------------------------------------------------------------------------
// Kernel 1: merged cast — x (16.78M floats) then Wq|Wk|Wv (3.15M floats).
// ---------------------------------------------------------------------------
__global__ __launch_bounds__(256) void k_cast_all(const float* __restrict__ X,
                                                  const float* __restrict__ Wq,
                                                  const float* __restrict__ Wk,
                                                  const float* __restrict__ Wv,
                                                  bf16* __restrict__ Xb,
                                                  bf16* __restrict__ Wb) {
  int i = blockIdx.x * 256 + threadIdx.x;
  const float* src;
  bf16* dst;
  int off;
  if (i < 4194304) {
    src = X; dst = Xb; off = i;
  } else {
    int j = i - 4194304;
    int which = j >> 18;
    src = (which == 0) ? Wq : ((which == 1) ? Wk : Wv);
    dst = Wb + (size_t)(j >> 18) * 1048576;
    off = j & 262143;
  }
  float4 v = ((const float4*)src)[off];
  bf16x4 o = {(bf16)v.x, (bf16)v.y, (bf16)v.z, (bf16)v.w};
  ((bf16x4*)dst)[off] = o;
}

// ---------------------------------------------------------------------------
// Kernel 2: QKV = Xb @ Wb^T (M=16384, N=3072, K=1024), bf16, ldc=3072.
//
// R7: 8-phase schedule, RACE-FIXED. BM=BN=256, BK=64, 512 thr (8 waves,
// 2Mx4N; per-wave 128x64 = acc[8][4], 16x16x32 MFMA). LDS 128 KiB = 2 bufs
// x [A slice0|A slice1|B slice0|B slice1] x 16 KiB (slice s = k-cols
// 32s..32s+31; within a slice: 128-row halves at +0/+8192; superrow
// rho=(row&127)>>1 (128 B), phys granule = logical ^ (rho&7); linear
// gload_lds dest + inverse-swizzled GLOBAL source. R5-verified 0-conflict).
//
// Staging units are ADDRESS halves: A_lo=rows 0..127, A_hi=rows 128..255
// (h in STG), same for B over output cols. Consumption by ADDRESS region
// (what R6 got wrong — it staged A_lo into the live buffer between the two
// phases that read it):
//   ph0 reads A bytes [0,4K)u[8K,12K) (frag rows i=0..3 of both wm-halves)
//       + B even 32-col groups;
//   ph1 reads B odd 32-col groups          -> B_lo & B_hi consumed;
//   ph2 reads A bytes [4K,8K)u[12K,16K)    -> A_lo & A_hi consumed;
//   ph3 regs only.
// Stage placement (each stage's target region fully read >=1 barrier ago):
//   ph0: A_hi(t+1) -> P^1   (P^1 A_hi last read at t-1 ph2)
//   ph1: (none)
//   ph2: B_lo(t+2) -> P     (B_lo consumed end ph1)
//   ph3: A_lo(t+2) -> P, B_hi(t+2) -> P  (consumed end ph2 / end ph1)
// vmcnt ledger (2 loads/unit): prologue = tile0 all 4 units + tile1
// {B_lo,A_lo,B_hi} = 14 loads -> vmcnt(6) lands tile0. Gate at end of t:
// outstanding = tile(t+1) 8 + tile(t+2) 6 = 14 -> vmcnt(6) lands t+1,
// keeps 6 in flight. t=14 -> vmcnt(0) (8 outstanding = tile15). t=15 none.
// sched_barrier(0) fences every waitcnt/barrier (rule 18).
// ---------------------------------------------------------------------------
__global__ __launch_bounds__(512, 2) void k_gemm_qkv(
    const bf16* __restrict__ X, const bf16* __restrict__ W,
    const int* __restrict__ lens, bf16* __restrict__ QKV) {
  // XCD-chunked bijective swizzle: 768 = 8 XCDs x 96; same-m-panel blocks
  // (12 consecutive ids) land on one XCD -> X panel L2-resident.
  const int bid = blockIdx.x;
  const int swz = (bid & 7) * 96 + (bid >> 3);
  const int m_blk = swz / 12;
  const int n_blk = swz - m_blk * 12;
  const int m0 = m_blk << 8, n0 = n_blk << 8;
  if (n0 >= 1024 && (m0 & 2047) >= lens[m0 >> 11]) return;  // block-uniform

  __shared__ __align__(16) char smem[131072];
  const char* smemc = (const char*)smem;

  const int tid = threadIdx.x;
  const int lane = tid & 63, wid = tid >> 6;
  const int mf = lane & 15, jb = lane >> 4;
  const int wm = (wid >> 2) * 128, wn = (wid & 3) * 64;

  // ds_read addressing (per 16KiB slice, R5-verified 0-conflict):
  const uint32_t pbyte = (uint32_t)(((((mf & 1) << 2) | jb) ^ ((mf >> 1) & 7)) * 16);
  const uint32_t rbase = (uint32_t)((mf >> 1) * 128) + pbyte;
#define LDA(i, ks, bof) (*(const bf16x8*)(smemc + (bof) + (ks) * 16384 + wm * 64 + (i) * 1024 + rbase))
#define LDB(j, ks, bof) (*(const bf16x8*)(smemc + (bof) + 32768 + (ks) * 16384 + wn * 64 + (j) * 1024 + rbase))

  // stage source geometry (inverse swizzle; verified elementwise R5/R7)
  const int sig = (tid & 7) ^ ((tid >> 3) & 7);
  const int rowbase = 2 * (tid >> 3) + (sig >> 2);  // 0..127 within half
  const int colb = (sig & 3) * 8;                   // slice-local col
  const bf16* gA = X + (size_t)(m0 + rowbase) * 1024 + colb;
  const bf16* gB = W + (size_t)(n0 + rowbase) * 1024 + colb;

  // unit stage: 2 x gload_lds (slice0, slice1). region: A=0, B=32768.
  // h = address half (rows/cols h*128 .. h*128+127).
#define STG(gp, region, h, kt, P)                                          \
  do {                                                                     \
    const bf16* s_ = (gp) + (size_t)(h) * 131072 + (size_t)(kt) * 64;      \
    char* d_ = smem + (size_t)(P) * 65536 + (region) + (h) * 8192 + wid * 1024; \
    async_copy16(s_,      (const bf16*)d_);                                \
    async_copy16(s_ + 32, (const bf16*)(d_ + 16384));                      \
  } while (0)

  bf16x8 af[4][2], blo[2][2], bhi[2][2];
  f32x4 acc[8][4] = {};

  // prologue: tile0 complete -> buf0; tile1 {B_lo, A_lo, B_hi} -> buf1
  // (A_hi(1) staged at t=0 ph0). 14 loads; vmcnt(6) lands tile 0.
  STG(gA, 0,     0, 0, 0);  // A_lo(0)
  STG(gB, 32768, 0, 0, 0);  // B_lo(0)
  STG(gB, 32768, 1, 0, 0);  // B_hi(0)
  STG(gA, 0,     1, 0, 0);  // A_hi(0)
  STG(gB, 32768, 0, 1, 1);  // B_lo(1)
  STG(gA, 0,     0, 1, 1);  // A_lo(1)
  STG(gB, 32768, 1, 1, 1);  // B_hi(1)
  asm volatile("s_waitcnt vmcnt(6)" ::: "memory");
  SB0();
  __builtin_amdgcn_s_barrier();
  SB0();

#pragma unroll 2
  for (int t = 0; t < 16; ++t) {
    const uint32_t bof = (uint32_t)(t & 1) << 16;
    const int P = t & 1;

    // ---------------- phase 0: frag-rows 0..3 x B-even ----------------
#pragma unroll
    for (int i = 0; i < 4; ++i) { af[i][0] = LDA(i, 0, bof); af[i][1] = LDA(i, 1, bof); }
#pragma unroll
    for (int j = 0; j < 2; ++j) { blo[j][0] = LDB(j, 0, bof); blo[j][1] = LDB(j, 1, bof); }
    if (t <= 14) STG(gA, 0, 1, t + 1, P ^ 1);  // A_hi(t+1): region idle since t-1 ph2
    asm volatile("s_waitcnt lgkmcnt(8)" ::: "memory");
    SB0();
    __builtin_amdgcn_s_barrier();
    asm volatile("s_waitcnt lgkmcnt(0)" ::: "memory");
    SB0();
    __builtin_amdgcn_s_setprio(1);
#pragma unroll
    for (int i = 0; i < 4; ++i)
#pragma unroll
      for (int j = 0; j < 2; ++j) {
        acc[i][j] = MF(af[i][0], blo[j][0], acc[i][j]);
        acc[i][j] = MF(af[i][1], blo[j][1], acc[i][j]);
      }
    __builtin_amdgcn_s_setprio(0);
    SB0();
    __builtin_amdgcn_s_barrier();
    SB0();

    // ---------------- phase 1: frag-rows 0..3 x B-odd ----------------
#pragma unroll
    for (int j = 0; j < 2; ++j) { bhi[j][0] = LDB(j + 2, 0, bof); bhi[j][1] = LDB(j + 2, 1, bof); }
    SB0();
    __builtin_amdgcn_s_barrier();
    asm volatile("s_waitcnt lgkmcnt(0)" ::: "memory");
    SB0();
    __builtin_amdgcn_s_setprio(1);
#pragma unroll
    for (int i = 0; i < 4; ++i)
#pragma unroll
      for (int j = 0; j < 2; ++j) {
        acc[i][j + 2] = MF(af[i][0], bhi[j][0], acc[i][j + 2]);
        acc[i][j + 2] = MF(af[i][1], bhi[j][1], acc[i][j + 2]);
      }
    __builtin_amdgcn_s_setprio(0);
    SB0();
    __builtin_amdgcn_s_barrier();
    SB0();

    // ---------------- phase 2: frag-rows 4..7 x B-odd ----------------
#pragma unroll
    for (int i = 0; i < 4; ++i) { af[i][0] = LDA(i + 4, 0, bof); af[i][1] = LDA(i + 4, 1, bof); }
    if (t <= 13) STG(gB, 32768, 0, t + 2, P);  // B_lo(t+2): consumed end ph1
    SB0();
    __builtin_amdgcn_s_barrier();
    asm volatile("s_waitcnt lgkmcnt(0)" ::: "memory");
    SB0();
    __builtin_amdgcn_s_setprio(1);
#pragma unroll
    for (int i = 0; i < 4; ++i)
#pragma unroll
      for (int j = 0; j < 2; ++j) {
        acc[i + 4][j + 2] = MF(af[i][0], bhi[j][0], acc[i + 4][j + 2]);
        acc[i + 4][j + 2] = MF(af[i][1], bhi[j][1], acc[i + 4][j + 2]);
      }
    __builtin_amdgcn_s_setprio(0);
    SB0();
    __builtin_amdgcn_s_barrier();
    SB0();

    // ---------------- phase 3: frag-rows 4..7 x B-even (regs only) ----
    if (t <= 13) {
      STG(gA, 0,     0, t + 2, P);  // A_lo(t+2): consumed end ph2
      STG(gB, 32768, 1, t + 2, P);  // B_hi(t+2): consumed end ph1
    }
    SB0();
    __builtin_amdgcn_s_setprio(1);
#pragma unroll
    for (int i = 0; i < 4; ++i)
#pragma unroll
      for (int j = 0; j < 2; ++j) {
        acc[i + 4][j] = MF(af[i][0], blo[j][0], acc[i + 4][j]);
        acc[i + 4][j] = MF(af[i][1], blo[j][1], acc[i + 4][j]);
      }
    __builtin_amdgcn_s_setprio(0);
    SB0();
    // gate for K-tile t+1 (counted: tile t+2's 6 loads stay in flight)
    if (t <= 13) {
      asm volatile("s_waitcnt vmcnt(6)" ::: "memory");
    } else if (t == 14) {
      asm volatile("s_waitcnt vmcnt(0)" ::: "memory");
    }
    if (t < 15) {
      SB0();
      __builtin_amdgcn_s_barrier();
      SB0();
    }
  }
#undef STG
#undef LDA
#undef LDB

  // epilogue: 16x16 C/D (m89/m91): col=lane&15, row=(lane>>4)*4+reg.
  const float qscale = (n0 < 1024) ? 0.03125f : 1.0f;  // block-uniform
  const int colw = n0 + wn + mf;
  const int roww = m0 + wm + jb * 4;
#pragma unroll
  for (int i = 0; i < 8; ++i)
#pragma unroll
    for (int r = 0; r < 4; ++r) {
      bf16* dst = QKV + (size_t)(roww + i * 16 + r) * 3072 + colw;
#pragma unroll
      for (int j = 0; j < 4; ++j) dst[j * 16] = (bf16)(acc[i][j][r] * qscale);
    }
}

// ---------------------------------------------------------------------------
// Kernel 3: transpose V part of QKV -> Vt[b][d][s]. Skip s-blocks >= kmax.
// ---------------------------------------------------------------------------
__global__ __launch_bounds__(256) void k_transpose_v(const bf16* __restrict__ QKV,
                                                     const int* __restrict__ lens,
                                                     bf16* __restrict__ Vt) {
  __shared__ bf16 tile[32][33];
  const int b = blockIdx.z;
  const int s0 = blockIdx.x * 32;
  if (s0 >= ((lens[b] + 63) & ~63)) return;
  const int d0 = blockIdx.y * 32;
  const int tx = threadIdx.x, ty = threadIdx.y;  // (32, 8)
#pragma unroll
  for (int i = 0; i < 4; ++i)
    tile[ty + i * 8][tx] = QKV[(size_t)(b * 2048 + s0 + ty + i * 8) * 3072 + 2048 + d0 + tx];
  __syncthreads();
#pragma unroll
  for (int i = 0; i < 4; ++i)
    Vt[(size_t)(b * 1024 + d0 + ty + i * 8) * 2048 + s0 + tx] = tile[tx][ty + i * 8];
}

// ---------------------------------------------------------------------------
// Kernel 4: S = Q @ K^T per batch (Q pre-scaled), bf16. 32x32x16 path.
// ---------------------------------------------------------------------------
__global__ __launch_bounds__(256) void k_gemm_scores(const bf16* __restrict__ QKV,
                                                     const int* __restrict__ lens,
                                                     bf16* __restrict__ S) {
  const int b = blockIdx.z;
  const int len = lens[b];
  const int n0 = blockIdx.x * 128;  // key tile
  if (n0 >= len) return;            // uniform per block
  const int m0 = blockIdx.y * 128;  // query tile
  __shared__ __align__(16) bf16 As[128 * 64];
  __shared__ __align__(16) bf16 Bs[128 * 64];
  const bf16* Q = QKV + (size_t)b * 2048 * 3072;
  const bf16* K = Q + 1024;
  f32x16 acc[2][2] = {};
  gemm_tile32(Q + (size_t)m0 * 3072, K + (size_t)n0 * 3072, 3072, 3072, 16, As, Bs, acc);
  bf16* Sb = S + (size_t)b * 2048 * 2048;
  EPILOGUE32(Sb[row * 2048 + col] = (bf16)val);
}

// ---------------------------------------------------------------------------
// Kernel 5: masked softmax per row, in place (S -> P).
// ---------------------------------------------------------------------------
__global__ __launch_bounds__(256) void k_softmax(bf16* __restrict__ S,
                                                 const int* __restrict__ lens) {
  const int row = blockIdx.x;  // 0..16383 (= b*2048 + q)
  const int len = lens[row >> 11];
  const int kmax = (len + 63) & ~63;
  bf16* Sr = S + (size_t)row * 2048;
  const int tid = threadIdx.x;
  const int base = tid * 8;
  __shared__ float red[4];

  float f[8];
  if (base < len) {
    bf16x8 v = ((const bf16x8*)Sr)[tid];
#pragma unroll
    for (int e = 0; e < 8; ++e) f[e] = (base + e < len) ? (float)v[e] : -1e30f;
  } else {
#pragma unroll
    for (int e = 0; e < 8; ++e) f[e] = -1e30f;
  }
  float m = -1e30f;
#pragma unroll
  for (int e = 0; e < 8; ++e) m = fmaxf(m, f[e]);
#pragma unroll
  for (int off = 32; off; off >>= 1) m = fmaxf(m, __shfl_xor(m, off));
  if ((tid & 63) == 0) red[tid >> 6] = m;
  __syncthreads();
  m = fmaxf(fmaxf(red[0], red[1]), fmaxf(red[2], red[3]));
  __syncthreads();

  float s = 0.f;
#pragma unroll
  for (int e = 0; e < 8; ++e) {
    float p = (base + e < len) ? __expf(f[e] - m) : 0.f;
    f[e] = p;
    s += p;
  }
#pragma unroll
  for (int off = 32; off; off >>= 1) s += __shfl_xor(s, off);
  if ((tid & 63) == 0) red[tid >> 6] = s;
  __syncthreads();
  s = red[0] + red[1] + red[2] + red[3];
  const float inv = 1.f / s;

  if (base < kmax) {
    bf16x8 o;
#pragma unroll
    for (int e = 0; e < 8; ++e) o[e] = (bf16)(f[e] * inv);
    ((bf16x8*)Sr)[tid] = o;
  }
}

// ---------------------------------------------------------------------------
// Kernel 6: O = P @ Vt^T per batch (M=2048, N=1024, K=ceil(len,64)), fp32.
// ---------------------------------------------------------------------------
__global__ __launch_bounds__(256) void k_gemm_out(const bf16* __restrict__ P,
                                                  const bf16* __restrict__ Vt,
                                                  const int* __restrict__ lens,
                                                  float* __restrict__ Out) {
  const int b = blockIdx.z;
  const int kTiles = (lens[b] + 63) >> 6;
  const int n0 = blockIdx.x * 128;  // over d (1024)
  const int m0 = blockIdx.y * 128;  // over queries
  __shared__ __align__(16) bf16 As[128 * 64];
  __shared__ __align__(16) bf16 Bs[128 * 64];
  const bf16* Pb = P + (size_t)b * 2048 * 2048;
  const bf16* Vb = Vt + (size_t)b * 1024 * 2048;
  f32x16 acc[2][2] = {};
  gemm_tile32(Pb + (size_t)m0 * 2048, Vb + (size_t)n0 * 2048, 2048, 2048, kTiles, As, Bs, acc);
  float* Ob = Out + (size_t)b * 2048 * 1024;
  EPILOGUE32(Ob[row * 1024 + col] = val);
}

// ---------------------------------------------------------------------------
// Workspace layout (bytes):
//   [0,   32M)   Xb   (dead after GEMM1)  \ overlapped by
//   [32M, 38M)   Wb   (dead after GEMM1)  /  S/P: [0, 64M)
//   [64M, 160M)  QKV  bf16 [16384][3072]
//   [160M,192M)  Vt   bf16 [8][1024][2048]
// ---------------------------------------------------------------------------
extern "C" void kernel_launch(void* const* d_in, const int* in_sizes, int n_in,
                              void* d_out, int out_size, void* d_ws, size_t ws_size,
                              hipStream_t stream) {
  const float* x   = (const float*)d_in[0];
  const int* lens  = (const int*)d_in[1];
  const float* Wq  = (const float*)d_in[2];
  const float* Wk  = (const float*)d_in[3];
  const float* Wv  = (const float*)d_in[4];
  float* out = (float*)d_out;

  char* ws = (char*)d_ws;
  bf16* S   = (bf16*)(ws);                 // 64 MiB (scores, then P in place)
  bf16* Xb  = (bf16*)(ws);                 // 32 MiB, overlaps S (dead first)
  bf16* Wb  = (bf16*)(ws + 33554432);      // 6 MiB, overlaps S
  bf16* QKV = (bf16*)(ws + 67108864);      // 96 MiB
  bf16* Vt  = (bf16*)(ws + 167772160);     // 32 MiB

  k_cast_all<<<19456, 256, 0, stream>>>(x, Wq, Wk, Wv, Xb, Wb);
  k_gemm_qkv<<<768, 512, 0, stream>>>(Xb, Wb, lens, QKV);
  k_transpose_v<<<dim3(64, 32, 8), dim3(32, 8), 0, stream>>>(QKV, lens, Vt);
  k_gemm_scores<<<dim3(16, 16, 8), 256, 0, stream>>>(QKV, lens, S);
  k_softmax<<<16384, 256, 0, stream>>>(S, lens);
  k_gemm_out<<<dim3(8, 16, 8), 256, 0, stream>>>(S, Vt, lens, out);
}